// Round 6
// baseline (126.451 us; speedup 1.0000x reference)
//
#include <hip/hip_runtime.h>
#include <hip/hip_fp16.h>
#include <math.h>

// Problem constants
constexpr int BS  = 8;
constexpr int NS  = 2048;
constexpr int NCP = 8;
constexpr int NH  = 8;
constexpr int C   = 128;
constexpr int HID = 128;
constexpr int RR  = 128;

constexpr int QPB = 8;    // queries per block (attn)
constexpr int VEC = 4;    // slots per thread (attn)

constexpr int NPOS = RR * RR;                       // 16384 positions per slab
constexpr size_t PLE = (size_t)BS * NPOS * C;       // elems per plane-type slab

// transpose geometry: 64 channels x 512 positions per tile (2 KB read chunks)
constexpr int CHB    = 64;
constexpr int PB     = 512;
constexpr int NBLK_T = 3 * BS * (C / CHB) * (NPOS / PB);   // 1536

// channel<->slot permutation (from the transpose packing):
//   chgrp = c>>6; within group: g = c&15, j = (c>>4)&3; slot = chgrp*64 + g*4 + j
__host__ __device__ __forceinline__ int slot_of_ch(int c) {
    return (c & 64) | ((c & 15) << 2) | ((c >> 4) & 3);
}
__host__ __device__ __forceinline__ int ch_of_slot(int s) {
    return (s & 64) | ((s & 3) << 4) | ((s >> 2) & 15);
}

typedef __attribute__((address_space(3))) float lds_f;
typedef const __attribute__((address_space(1))) float glb_f;

// ---------------------------------------------------------------------------
struct F4 { float x, y, z, w; };
__device__ __forceinline__ F4 f4add(F4 a, F4 b) {
    return F4{a.x + b.x, a.y + b.y, a.z + b.z, a.w + b.w};
}
__device__ __forceinline__ F4 f4fma(F4 acc, float s, F4 v) {
    return F4{fmaf(s, v.x, acc.x), fmaf(s, v.y, acc.y),
              fmaf(s, v.z, acc.z), fmaf(s, v.w, acc.w)};
}
__device__ __forceinline__ F4 cvt4(int2 r) {
    __half2 h0 = *reinterpret_cast<__half2*>(&r.x);
    __half2 h1 = *reinterpret_cast<__half2*>(&r.y);
    float2 f0 = __half22float2(h0);
    float2 f1 = __half22float2(h1);
    return F4{f0.x, f0.y, f1.x, f1.y};
}

// ---------------------------------------------------------------------------
// Fused transpose (fp32 [C][R][R] -> fp16 [R*R][slot]) + weight prep.
// Tile = 64 ch x 512 pos: each channel read is one 2 KB sequential chunk
// (2 x global_load_lds width-16), XOR-swizzled on the SOURCE so the
// transposed LDS read is a uniform 2-way bank pattern.
// Blocks [0, 1536): transpose tiles. Blocks [1536, 1666): weight prep.
// ---------------------------------------------------------------------------
__global__ __launch_bounds__(256) void trans_prep_k(
    const float* __restrict__ pxz, const float* __restrict__ pxy,
    const float* __restrict__ pyz, __half* __restrict__ dst,
    const float* __restrict__ Wv, const float* __restrict__ bv,
    const float* __restrict__ Ww, const float* __restrict__ bw,
    const float* __restrict__ Wo,
    float* __restrict__ Wf, float* __restrict__ bf,
    float* __restrict__ Ww2, float* __restrict__ bw2)
{
    __shared__ float lds[CHB * PB];   // 128 KB (gfx950 allows >64 KB LDS/WG)

    const int bid = blockIdx.x;
    const int t   = threadIdx.x;

    if (bid >= NBLK_T) {
        // ----- weight prep (slot-permuted rows) -----
        const int k = bid - NBLK_T;
        const int c = t;
        if (c >= 128) return;
        if (k < 128) {
            // Wf[slot k][c] = sum_j Wv[ch(k)][j] * Wo[j][c]
            const int kk = ch_of_slot(k);
            float acc = 0.f;
            #pragma unroll 8
            for (int j = 0; j < 128; ++j) acc += Wv[kk * 128 + j] * Wo[j * 128 + c];
            Wf[k * 128 + c] = acc;
        } else if (k == 128) {
            float acc = 0.f;
            #pragma unroll 8
            for (int j = 0; j < 128; ++j) acc += bv[j] * Wo[j * 128 + c];
            bf[c] = acc;
        } else {  // k == 129: Ww2[slot c][h] = sum_i Ww[ch(c)][i*8+h]
            const int cc = ch_of_slot(c);
            float s[NH];
            #pragma unroll
            for (int h = 0; h < NH; ++h) s[h] = 0.f;
            #pragma unroll
            for (int i = 0; i < NCP; ++i)
                #pragma unroll
                for (int h = 0; h < NH; ++h) s[h] += Ww[cc * (NCP * NH) + i * NH + h];
            #pragma unroll
            for (int h = 0; h < NH; ++h) Ww2[c * NH + h] = s[h];
            if (c < NH) {
                float tt = 0.f;
                #pragma unroll
                for (int i = 0; i < NCP; ++i) tt += bw[i * NH + c];
                bw2[c] = tt;
            }
        }
        return;
    }

    // ----- transpose tile -----
    // XCD-align: batch = bid & 7 so batch b's planes are produced on XCD b.
    const int b   = bid & 7;
    const int idx = bid >> 3;             // 0..191
    const int pl  = idx >> 6;             // 0..2
    const int r   = idx & 63;
    const int cg  = r & 1;                // channel group (0/1)
    const int pg  = r >> 1;               // position group (0..31)
    const int c0  = cg * CHB;
    const int n0  = pg * PB;

    const float* src = (pl == 0 ? pxz : (pl == 1 ? pxy : pyz))
                       + (size_t)b * C * NPOS + (size_t)c0 * NPOS;
    __half* d = dst + (size_t)(pl * BS + b) * ((size_t)NPOS * C);

    const int wave = t >> 6;
    const int lane = t & 63;

    // Phase A: async stage. Per wave: 16 channels x 2 instrs (1 KB each).
    // Channel cl's 2 KB chunk is sequential in global; within each 1 KB
    // half, the 64 16B-blocks are XOR-permuted by s = cl & 15 (T21).
    #pragma unroll
    for (int k = 0; k < 32; ++k) {
        const int cl   = wave * 16 + (k >> 1);
        const int half = k & 1;
        const int s    = cl & 15;
        glb_f* gp = (glb_f*)(src + (size_t)cl * NPOS + n0
                             + (((half << 6) + (lane ^ s)) << 2));
        lds_f* lp = (lds_f*)(&lds[cl * PB + half * 256]);
        __builtin_amdgcn_global_load_lds(gp, lp, 16, 0, 0);
    }
    __syncthreads();   // drains vmcnt (compiler-inserted) before reads

    // Phase B: transposed read (uniform 2-way bank pattern) + fp16 pack +
    // 8 B/lane coalesced store (16 lanes -> 128 B contiguous per position).
    #pragma unroll
    for (int it = 0; it < 32; ++it) {
        const int li = it * 256 + t;
        const int n  = li >> 4;           // 0..511
        const int g  = li & 15;
        const int bp = (((n >> 2) ^ g) << 2) + (n & 3);  // swizzled pos offset
        float f[4];
        #pragma unroll
        for (int j = 0; j < 4; ++j)
            f[j] = lds[(g + 16 * j) * PB + bp];
        __half2 h01 = __floats2half2_rn(f[0], f[1]);
        __half2 h23 = __floats2half2_rn(f[2], f[3]);
        uint2 v;
        v.x = *reinterpret_cast<unsigned*>(&h01);
        v.y = *reinterpret_cast<unsigned*>(&h23);
        *reinterpret_cast<uint2*>(d + (size_t)(n0 + n) * C + c0 + g * 4) = v;
    }
}

// ---------------------------------------------------------------------------
// Bilinear sample of 4 fp16 slots; base already offset by batch + slot4.
// ---------------------------------------------------------------------------
__device__ __forceinline__ F4 samp(const __half* __restrict__ base, float u, float v)
{
    float x = fminf(fmaxf(u, 0.f), 1.f) * (float)(RR - 1);
    float y = fminf(fmaxf(v, 0.f), 1.f) * (float)(RR - 1);
    float x0f = floorf(x), y0f = floorf(y);
    float wx = x - x0f, wy = y - y0f;
    int x0 = (int)x0f, y0 = (int)y0f;
    int x1 = min(x0 + 1, RR - 1), y1 = min(y0 + 1, RR - 1);
    int r0 = y0 << 14, r1 = y1 << 14, cc0 = x0 << 7, cc1 = x1 << 7;
    int2 a00 = *reinterpret_cast<const int2*>(base + r0 + cc0);
    int2 a01 = *reinterpret_cast<const int2*>(base + r0 + cc1);
    int2 a10 = *reinterpret_cast<const int2*>(base + r1 + cc0);
    int2 a11 = *reinterpret_cast<const int2*>(base + r1 + cc1);
    float w00 = (1.f - wx) * (1.f - wy), w01 = wx * (1.f - wy);
    float w10 = (1.f - wx) * wy,         w11 = wx * wy;
    F4 f00 = cvt4(a00), f01 = cvt4(a01), f10 = cvt4(a10), f11 = cvt4(a11);
    F4 r;
    r.x = f00.x * w00 + f01.x * w01 + f10.x * w10 + f11.x * w11;
    r.y = f00.y * w00 + f01.y * w01 + f10.y * w10 + f11.y * w11;
    r.z = f00.z * w00 + f01.z * w01 + f10.z * w10 + f11.z * w11;
    r.w = f00.w * w00 + f01.w * w01 + f10.w * w10 + f11.w * w11;
    return r;
}

// ---------------------------------------------------------------------------
// Main fused kernel: 256 threads = 8 queries x 32 threads (4 slots each).
// Planes/weights are in slot (permuted-channel) order; output in original.
// ---------------------------------------------------------------------------
__global__ __launch_bounds__(256) void attn_k(
    const float* __restrict__ qpos,
    const __half* __restrict__ planes,   // [3][B][R][R][slot] fp16
    const float* __restrict__ cpts,
    const float* __restrict__ Ww2, const float* __restrict__ bw2,
    const float* __restrict__ Wf,  const float* __restrict__ bf,
    const float* __restrict__ bo,
    float* __restrict__ out)
{
    // XCD-aware swizzle (gridDim.x = 2048, divisible by 8)
    const int nb   = gridDim.x;
    const int cpx  = nb >> 3;
    const int sbid = (blockIdx.x & 7) * cpx + (blockIdx.x >> 3);

    const int tid  = threadIdx.x;
    const int ql   = tid >> 5;
    const int lane = tid & 31;
    const int c4   = lane * VEC;       // slot index
    const int q    = sbid * QPB + ql;
    const int b    = q >> 11;          // q / NS

    const float* qp = qpos + (size_t)q * 9;
    const float px = qp[0], py = qp[1], pz = qp[2];
    const float a1x = qp[3], a1y = qp[4], a1z = qp[5];
    const float a2x = qp[6], a2y = qp[7], a2z = qp[8];

    float inv = 1.f / sqrtf(a1x * a1x + a1y * a1y + a1z * a1z);
    float b1x = a1x * inv, b1y = a1y * inv, b1z = a1z * inv;
    float dd  = b1x * a2x + b1y * a2y + b1z * a2z;
    float b2x = a2x - dd * b1x, b2y = a2y - dd * b1y, b2z = a2z - dd * b1z;
    inv = 1.f / sqrtf(b2x * b2x + b2y * b2y + b2z * b2z);
    b2x *= inv; b2y *= inv; b2z *= inv;
    float b3x = b1y * b2z - b1z * b2y;
    float b3y = b1z * b2x - b1x * b2z;
    float b3z = b1x * b2y - b1y * b2x;

    const __half* Pxz = planes + (size_t)b * ((size_t)NPOS * C) + c4;
    const __half* Pxy = Pxz + PLE;
    const __half* Pyz = Pxy + PLE;

    // ---- pass 1: base feature (4 slots) ----
    F4 feat = f4add(f4add(samp(Pxz, px, pz), samp(Pxy, px, py)), samp(Pyz, py, pz));

    // ---- ws[h] = feat . Ww2[:,h] + bw2[h] (Ww2 already slot-permuted) ----
    float p[NH];
    #pragma unroll
    for (int h = 0; h < NH; ++h) p[h] = 0.f;
    {
        const float* wr = Ww2 + c4 * NH;
        const float fv[VEC] = {feat.x, feat.y, feat.z, feat.w};
        #pragma unroll
        for (int i = 0; i < VEC; ++i)
            #pragma unroll
            for (int h = 0; h < NH; ++h) p[h] += fv[i] * wr[i * NH + h];
    }
    #pragma unroll
    for (int off = 16; off >= 1; off >>= 1)
        #pragma unroll
        for (int h = 0; h < NH; ++h) p[h] += __shfl_xor(p[h], off);

    float ws[NH], Ssum = 0.f;
    #pragma unroll
    for (int h = 0; h < NH; ++h) { ws[h] = p[h] + bw2[h]; Ssum += ws[h]; }

    // ---- pass 2: anchors, accumulate comb = sum_g ws[g]*sf[g] ----
    F4 comb = {0.f, 0.f, 0.f, 0.f};
    #pragma unroll 2
    for (int g = 0; g < NCP; ++g) {
        float cx = cpts[g * 3 + 0], cy = cpts[g * 3 + 1], cz = cpts[g * 3 + 2];
        float ax = px + b1x * cx + b1y * cy + b1z * cz;
        float ay = py + b2x * cx + b2y * cy + b2z * cz;
        float az = pz + b3x * cx + b3y * cy + b3z * cz;
        F4 s = f4add(f4add(samp(Pxz, ax, az), samp(Pxy, ax, ay)), samp(Pyz, ay, az));
        comb = f4fma(comb, ws[g], s);
    }

    // ---- stash per-query vectors (slot order) ----
    __shared__ float sComb[QPB][C];
    __shared__ float sFeat[QPB][C];
    __shared__ float sSum[QPB];
    *reinterpret_cast<float4*>(&sComb[ql][c4]) = make_float4(comb.x, comb.y, comb.z, comb.w);
    *reinterpret_cast<float4*>(&sFeat[ql][c4]) = make_float4(feat.x, feat.y, feat.z, feat.w);
    if (lane == 0) sSum[ql] = Ssum;
    __syncthreads();

    // ---- epilogue GEMV: out[c] = comb_slot . Wf[:,c] + Ssum*bf[c] + bo[c] + feat[c]
    const int c  = tid & 127;         // original output channel
    const int sl = slot_of_ch(c);     // where feat[c] lives in slot order
    const int q0 = (tid >> 7) * 4;    // queries q0..q0+3
    float acc[4];
    const float bfc = bf[c], boc = bo[c];
    #pragma unroll
    for (int j = 0; j < 4; ++j)
        acc[j] = sSum[q0 + j] * bfc + boc + sFeat[q0 + j][sl];
    #pragma unroll 4
    for (int k = 0; k < C; ++k) {
        float wf = Wf[k * C + c];
        #pragma unroll
        for (int j = 0; j < 4; ++j) acc[j] += sComb[q0 + j][k] * wf;
    }
    #pragma unroll
    for (int j = 0; j < 4; ++j)
        out[(size_t)(sbid * QPB + q0 + j) * C + c] = acc[j];
}

// ---------------------------------------------------------------------------
extern "C" void kernel_launch(void* const* d_in, const int* in_sizes, int n_in,
                              void* d_out, int out_size, void* d_ws, size_t ws_size,
                              hipStream_t stream)
{
    const float* qpos = (const float*)d_in[0];
    const float* pxz  = (const float*)d_in[1];
    const float* pxy  = (const float*)d_in[2];
    const float* pyz  = (const float*)d_in[3];
    const float* cpts = (const float*)d_in[4];
    const float* Wv   = (const float*)d_in[5];
    const float* bv   = (const float*)d_in[6];
    const float* Ww   = (const float*)d_in[7];
    const float* bw   = (const float*)d_in[8];
    const float* Wo   = (const float*)d_in[9];
    const float* bo   = (const float*)d_in[10];
    float* out = (float*)d_out;

    __half* plh = (__half*)d_ws;
    float*  wsf = (float*)((char*)d_ws + 3 * PLE * sizeof(__half));  // ~96 MB in
    float* Wf  = wsf;                 // 128*128
    float* bf  = Wf + C * HID;        // 128
    float* Ww2 = bf + C;              // 128*8
    float* bw2 = Ww2 + C * NH;        // 8

    // fused transpose + weight prep
    hipLaunchKernelGGL(trans_prep_k, dim3(NBLK_T + 130), dim3(256), 0, stream,
                       pxz, pxy, pyz, plh, Wv, bv, Ww, bw, Wo, Wf, bf, Ww2, bw2);

    // fused main kernel
    hipLaunchKernelGGL(attn_k, dim3(BS * NS / QPB), dim3(256), 0, stream,
                       qpos, plh, cpts, Ww2, bw2, Wf, bf, bo, out);
}

// Round 7
// 125.683 us; speedup vs baseline: 1.0061x; 1.0061x over previous
//
#include <hip/hip_runtime.h>
#include <hip/hip_fp16.h>
#include <math.h>

// Problem constants
constexpr int BS  = 8;
constexpr int NS  = 2048;
constexpr int NCP = 8;
constexpr int NH  = 8;
constexpr int C   = 128;
constexpr int HID = 128;
constexpr int RR  = 128;

constexpr int QPB = 8;    // queries per block (attn)
constexpr int VEC = 4;    // channels per thread (attn)

constexpr int NPOS = RR * RR;                       // 16384 positions per slab
constexpr size_t PLE = (size_t)BS * NPOS * C;       // elems per plane-type slab

// transpose: 768 blocks = 24 slabs x 2 halves x 16 channel-groups.
// Each block: 8 channels x 8192 positions. Reads LINEAR (8 x 32KB runs),
// writes 16B/position at 256B stride -> combined to full lines in the
// slab's XCD L2 (all 16 groups of a slab pinned to one XCD, co-running).
constexpr int NBLK_T = 768;
constexpr int HPOS   = 8192;     // positions per half
constexpr int SCPOS  = 1024;     // positions per LDS sub-chunk
constexpr int LROW   = 1032;     // LDS row stride in halves (pad 8)

using f4v = __attribute__((ext_vector_type(4))) float;

// ---------------------------------------------------------------------------
struct F4 { float x, y, z, w; };
__device__ __forceinline__ F4 f4add(F4 a, F4 b) {
    return F4{a.x + b.x, a.y + b.y, a.z + b.z, a.w + b.w};
}
__device__ __forceinline__ F4 f4fma(F4 acc, float s, F4 v) {
    return F4{fmaf(s, v.x, acc.x), fmaf(s, v.y, acc.y),
              fmaf(s, v.z, acc.z), fmaf(s, v.w, acc.w)};
}
__device__ __forceinline__ F4 cvt4(int2 r) {
    __half2 h0 = *reinterpret_cast<__half2*>(&r.x);
    __half2 h1 = *reinterpret_cast<__half2*>(&r.y);
    float2 f0 = __half22float2(h0);
    float2 f1 = __half22float2(h1);
    return F4{f0.x, f0.y, f1.x, f1.y};
}

// ---------------------------------------------------------------------------
// Fused transpose (fp32 [C][R][R] -> fp16 [R*R][C]) + weight prep.
// Blocks [0, 768): transpose. Blocks [768, 898): weight prep.
// ---------------------------------------------------------------------------
__global__ __launch_bounds__(256) void trans_prep_k(
    const float* __restrict__ pxz, const float* __restrict__ pxy,
    const float* __restrict__ pyz, __half* __restrict__ dst,
    const float* __restrict__ Wv, const float* __restrict__ bv,
    const float* __restrict__ Ww, const float* __restrict__ bw,
    const float* __restrict__ Wo,
    float* __restrict__ Wf, float* __restrict__ bf,
    float* __restrict__ Ww2, float* __restrict__ bw2)
{
    __shared__ __half lh[8 * LROW];   // 16.5 KB

    const int bid = blockIdx.x;
    const int t   = threadIdx.x;

    if (bid >= NBLK_T) {
        // ----- weight prep (natural channel order) -----
        const int k = bid - NBLK_T;
        const int c = t;
        if (c >= 128) return;
        if (k < 128) {
            float acc = 0.f;
            #pragma unroll 8
            for (int j = 0; j < 128; ++j) acc += Wv[k * 128 + j] * Wo[j * 128 + c];
            Wf[k * 128 + c] = acc;
        } else if (k == 128) {
            float acc = 0.f;
            #pragma unroll 8
            for (int j = 0; j < 128; ++j) acc += bv[j] * Wo[j * 128 + c];
            bf[c] = acc;
        } else {  // k == 129
            float s[NH];
            #pragma unroll
            for (int h = 0; h < NH; ++h) s[h] = 0.f;
            #pragma unroll
            for (int i = 0; i < NCP; ++i)
                #pragma unroll
                for (int h = 0; h < NH; ++h) s[h] += Ww[c * (NCP * NH) + i * NH + h];
            #pragma unroll
            for (int h = 0; h < NH; ++h) Ww2[c * NH + h] = s[h];
            if (c < NH) {
                float tt = 0.f;
                #pragma unroll
                for (int i = 0; i < NCP; ++i) tt += bw[i * NH + c];
                bw2[c] = tt;
            }
        }
        return;
    }

    // ----- transpose block -----
    // bid = xcd + 8*( pl*32 + h*16 + g ): slab (pl, b=xcd) pinned to XCD b,
    // with channel-group g fastest-varying so a slab's 16 groups co-run and
    // their 16B-stripe writes combine to full lines in that XCD's L2.
    const int xcd = bid & 7;
    const int rem = bid >> 3;            // 0..95
    const int pl  = rem >> 5;            // 0..2
    const int kk  = rem & 31;
    const int hh  = kk >> 4;             // half 0/1
    const int g   = kk & 15;             // channel group
    const int b   = xcd;

    const float* base = (pl == 0 ? pxz : (pl == 1 ? pxy : pyz));
    const float* src = base + (size_t)b * C * NPOS + (size_t)(g * 8) * NPOS
                            + (size_t)hh * HPOS;
    __half* d = dst + (size_t)(pl * BS + b) * ((size_t)NPOS * C)
                    + (size_t)hh * HPOS * C + g * 8;

    const int cl  = t >> 5;              // channel within group (0..7)
    const int l32 = t & 31;

    const float* sp0 = src + (size_t)cl * NPOS + l32 * 4;

    // prologue: load sub-chunk 0 (nontemporal: don't evict L2 write lines)
    f4v v[8];
    #pragma unroll
    for (int j = 0; j < 8; ++j)
        v[j] = __builtin_nontemporal_load(
                   reinterpret_cast<const f4v*>(sp0 + j * 128));

    #pragma unroll
    for (int sc = 0; sc < 8; ++sc) {
        __syncthreads();   // protect previous sub-chunk's LDS reads

        // fp32 -> fp16, write [8ch][1024pos] rows (8B contiguous per lane)
        #pragma unroll
        for (int j = 0; j < 8; ++j) {
            __half2 h0 = __floats2half2_rn(v[j][0], v[j][1]);
            __half2 h1 = __floats2half2_rn(v[j][2], v[j][3]);
            uint2 w;
            w.x = *reinterpret_cast<unsigned*>(&h0);
            w.y = *reinterpret_cast<unsigned*>(&h1);
            *reinterpret_cast<uint2*>(&lh[cl * LROW + l32 * 4 + j * 128]) = w;
        }

        // issue next sub-chunk's loads early (hide under store phase)
        f4v nv[8];
        if (sc < 7) {
            const float* sp = sp0 + (sc + 1) * SCPOS;
            #pragma unroll
            for (int j = 0; j < 8; ++j)
                nv[j] = __builtin_nontemporal_load(
                            reinterpret_cast<const f4v*>(sp + j * 128));
        }
        __syncthreads();

        // transposed read (2 lanes/bank = free) + pack + 16B stripe store
        #pragma unroll
        for (int i = 0; i < 4; ++i) {
            const int p = t + i * 256;
            unsigned short r[8];
            #pragma unroll
            for (int j = 0; j < 8; ++j)
                r[j] = *reinterpret_cast<const unsigned short*>(&lh[j * LROW + p]);
            uint4 u;
            u.x = (unsigned)r[0] | ((unsigned)r[1] << 16);
            u.y = (unsigned)r[2] | ((unsigned)r[3] << 16);
            u.z = (unsigned)r[4] | ((unsigned)r[5] << 16);
            u.w = (unsigned)r[6] | ((unsigned)r[7] << 16);
            *reinterpret_cast<uint4*>(d + (size_t)(sc * SCPOS + p) * C) = u;
        }

        #pragma unroll
        for (int j = 0; j < 8; ++j) v[j] = nv[j];
    }
}

// ---------------------------------------------------------------------------
// Bilinear sample of 4 fp16 channels; base already offset by batch + c4.
// ---------------------------------------------------------------------------
__device__ __forceinline__ F4 samp(const __half* __restrict__ base, float u, float v)
{
    float x = fminf(fmaxf(u, 0.f), 1.f) * (float)(RR - 1);
    float y = fminf(fmaxf(v, 0.f), 1.f) * (float)(RR - 1);
    float x0f = floorf(x), y0f = floorf(y);
    float wx = x - x0f, wy = y - y0f;
    int x0 = (int)x0f, y0 = (int)y0f;
    int x1 = min(x0 + 1, RR - 1), y1 = min(y0 + 1, RR - 1);
    int r0 = y0 << 14, r1 = y1 << 14, cc0 = x0 << 7, cc1 = x1 << 7;
    int2 a00 = *reinterpret_cast<const int2*>(base + r0 + cc0);
    int2 a01 = *reinterpret_cast<const int2*>(base + r0 + cc1);
    int2 a10 = *reinterpret_cast<const int2*>(base + r1 + cc0);
    int2 a11 = *reinterpret_cast<const int2*>(base + r1 + cc1);
    float w00 = (1.f - wx) * (1.f - wy), w01 = wx * (1.f - wy);
    float w10 = (1.f - wx) * wy,         w11 = wx * wy;
    F4 f00 = cvt4(a00), f01 = cvt4(a01), f10 = cvt4(a10), f11 = cvt4(a11);
    F4 r;
    r.x = f00.x * w00 + f01.x * w01 + f10.x * w10 + f11.x * w11;
    r.y = f00.y * w00 + f01.y * w01 + f10.y * w10 + f11.y * w11;
    r.z = f00.z * w00 + f01.z * w01 + f10.z * w10 + f11.z * w11;
    r.w = f00.w * w00 + f01.w * w01 + f10.w * w10 + f11.w * w11;
    return r;
}

// ---------------------------------------------------------------------------
// Main fused kernel: 256 threads = 8 queries x 32 threads (4 channels each).
// ---------------------------------------------------------------------------
__global__ __launch_bounds__(256) void attn_k(
    const float* __restrict__ qpos,
    const __half* __restrict__ planes,   // [3][B][R][R][C] fp16
    const float* __restrict__ cpts,
    const float* __restrict__ Ww2, const float* __restrict__ bw2,
    const float* __restrict__ Wf,  const float* __restrict__ bf,
    const float* __restrict__ bo,
    float* __restrict__ out)
{
    // XCD-aware swizzle (gridDim.x = 2048, divisible by 8): batch b -> XCD b,
    // matching the transpose's slab pinning (fp16 planes L2-warm).
    const int nb   = gridDim.x;
    const int cpx  = nb >> 3;
    const int sbid = (blockIdx.x & 7) * cpx + (blockIdx.x >> 3);

    const int tid  = threadIdx.x;
    const int ql   = tid >> 5;
    const int lane = tid & 31;
    const int c4   = lane * VEC;
    const int q    = sbid * QPB + ql;
    const int b    = q >> 11;          // q / NS

    const float* qp = qpos + (size_t)q * 9;
    const float px = qp[0], py = qp[1], pz = qp[2];
    const float a1x = qp[3], a1y = qp[4], a1z = qp[5];
    const float a2x = qp[6], a2y = qp[7], a2z = qp[8];

    float inv = 1.f / sqrtf(a1x * a1x + a1y * a1y + a1z * a1z);
    float b1x = a1x * inv, b1y = a1y * inv, b1z = a1z * inv;
    float dd  = b1x * a2x + b1y * a2y + b1z * a2z;
    float b2x = a2x - dd * b1x, b2y = a2y - dd * b1y, b2z = a2z - dd * b1z;
    inv = 1.f / sqrtf(b2x * b2x + b2y * b2y + b2z * b2z);
    b2x *= inv; b2y *= inv; b2z *= inv;
    float b3x = b1y * b2z - b1z * b2y;
    float b3y = b1z * b2x - b1x * b2z;
    float b3z = b1x * b2y - b1y * b2x;

    const __half* Pxz = planes + (size_t)b * ((size_t)NPOS * C) + c4;
    const __half* Pxy = Pxz + PLE;
    const __half* Pyz = Pxy + PLE;

    // ---- pass 1: base feature (4 channels) ----
    F4 feat = f4add(f4add(samp(Pxz, px, pz), samp(Pxy, px, py)), samp(Pyz, py, pz));

    // ---- ws[h] = feat . Ww2[:,h] + bw2[h], reduced over the 32-lane group --
    float p[NH];
    #pragma unroll
    for (int h = 0; h < NH; ++h) p[h] = 0.f;
    {
        const float* wr = Ww2 + c4 * NH;
        const float fv[VEC] = {feat.x, feat.y, feat.z, feat.w};
        #pragma unroll
        for (int i = 0; i < VEC; ++i)
            #pragma unroll
            for (int h = 0; h < NH; ++h) p[h] += fv[i] * wr[i * NH + h];
    }
    #pragma unroll
    for (int off = 16; off >= 1; off >>= 1)
        #pragma unroll
        for (int h = 0; h < NH; ++h) p[h] += __shfl_xor(p[h], off);

    float ws[NH], Ssum = 0.f;
    #pragma unroll
    for (int h = 0; h < NH; ++h) { ws[h] = p[h] + bw2[h]; Ssum += ws[h]; }

    // ---- pass 2: anchors, accumulate comb = sum_g ws[g]*sf[g] ----
    F4 comb = {0.f, 0.f, 0.f, 0.f};
    #pragma unroll 2
    for (int g = 0; g < NCP; ++g) {
        float cx = cpts[g * 3 + 0], cy = cpts[g * 3 + 1], cz = cpts[g * 3 + 2];
        float ax = px + b1x * cx + b1y * cy + b1z * cz;
        float ay = py + b2x * cx + b2y * cy + b2z * cz;
        float az = pz + b3x * cx + b3y * cy + b3z * cz;
        F4 s = f4add(f4add(samp(Pxz, ax, az), samp(Pxy, ax, ay)), samp(Pyz, ay, az));
        comb = f4fma(comb, ws[g], s);
    }

    // ---- stash per-query vectors ----
    __shared__ float sComb[QPB][C];
    __shared__ float sFeat[QPB][C];
    __shared__ float sSum[QPB];
    *reinterpret_cast<float4*>(&sComb[ql][c4]) = make_float4(comb.x, comb.y, comb.z, comb.w);
    *reinterpret_cast<float4*>(&sFeat[ql][c4]) = make_float4(feat.x, feat.y, feat.z, feat.w);
    if (lane == 0) sSum[ql] = Ssum;
    __syncthreads();

    // ---- epilogue GEMV: out[c] = comb.Wf[:,c] + Ssum*bf[c] + bo[c] + feat[c]
    const int c  = tid & 127;
    const int q0 = (tid >> 7) * 4;    // queries q0..q0+3
    float acc[4];
    const float bfc = bf[c], boc = bo[c];
    #pragma unroll
    for (int j = 0; j < 4; ++j)
        acc[j] = sSum[q0 + j] * bfc + boc + sFeat[q0 + j][c];
    #pragma unroll 4
    for (int k = 0; k < C; ++k) {
        float wf = Wf[k * C + c];
        #pragma unroll
        for (int j = 0; j < 4; ++j) acc[j] += sComb[q0 + j][k] * wf;
    }
    #pragma unroll
    for (int j = 0; j < 4; ++j)
        out[(size_t)(sbid * QPB + q0 + j) * C + c] = acc[j];
}

// ---------------------------------------------------------------------------
extern "C" void kernel_launch(void* const* d_in, const int* in_sizes, int n_in,
                              void* d_out, int out_size, void* d_ws, size_t ws_size,
                              hipStream_t stream)
{
    const float* qpos = (const float*)d_in[0];
    const float* pxz  = (const float*)d_in[1];
    const float* pxy  = (const float*)d_in[2];
    const float* pyz  = (const float*)d_in[3];
    const float* cpts = (const float*)d_in[4];
    const float* Wv   = (const float*)d_in[5];
    const float* bv   = (const float*)d_in[6];
    const float* Ww   = (const float*)d_in[7];
    const float* bw   = (const float*)d_in[8];
    const float* Wo   = (const float*)d_in[9];
    const float* bo   = (const float*)d_in[10];
    float* out = (float*)d_out;

    __half* plh = (__half*)d_ws;
    float*  wsf = (float*)((char*)d_ws + 3 * PLE * sizeof(__half));  // ~96 MB in
    float* Wf  = wsf;                 // 128*128
    float* bf  = Wf + C * HID;        // 128
    float* Ww2 = bf + C;              // 128*8
    float* bw2 = Ww2 + C * NH;        // 8

    // fused transpose + weight prep
    hipLaunchKernelGGL(trans_prep_k, dim3(NBLK_T + 130), dim3(256), 0, stream,
                       pxz, pxy, pyz, plh, Wv, bv, Ww, bw, Wo, Wf, bf, Ww2, bw2);

    // fused main kernel
    hipLaunchKernelGGL(attn_k, dim3(BS * NS / QPB), dim3(256), 0, stream,
                       qpos, plh, cpts, Ww2, bw2, Wf, bf, bo, out);
}